// Round 2
// baseline (456.076 us; speedup 1.0000x reference)
//
#include <hip/hip_runtime.h>
#include <hip/hip_bf16.h>

#define DIV_UP(a,b) (((a)+(b)-1)/(b))

typedef __attribute__((ext_vector_type(8))) short short8;
typedef __attribute__((ext_vector_type(4))) float floatx4;

// ---------- bf16 helpers (manual, deterministic RNE) ----------
static __device__ __forceinline__ unsigned short f2bf(float v) {
    unsigned u = __builtin_bit_cast(unsigned, v);
    u += 0x7fffu + ((u >> 16) & 1u);
    return (unsigned short)(u >> 16);
}
static __device__ __forceinline__ float bflo(unsigned v) {
    return __builtin_bit_cast(float, v << 16);
}
static __device__ __forceinline__ float bfhi(unsigned v) {
    return __builtin_bit_cast(float, v & 0xffff0000u);
}
static __device__ __forceinline__ float fexp2(float x) { return __builtin_amdgcn_exp2f(x); }
static __device__ __forceinline__ float f4get(const float4 v, int k) {
    return k == 0 ? v.x : k == 1 ? v.y : k == 2 ? v.z : v.w;
}

// raw per-lane x-row slice type by channels-per-lane
template <int CPL> struct RawT;
template <> struct RawT<8> { using T = uint4; };
template <> struct RawT<4> { using T = uint2; };
template <> struct RawT<2> { using T = unsigned; };

template <int CPL>
static __device__ __forceinline__ void unpackx(const typename RawT<CPL>::T& v, float* d) {
    if constexpr (CPL == 8) {
        d[0] = bflo(v.x); d[1] = bfhi(v.x);
        d[2] = bflo(v.y); d[3] = bfhi(v.y);
        d[4] = bflo(v.z); d[5] = bfhi(v.z);
        d[6] = bflo(v.w); d[7] = bfhi(v.w);
    } else if constexpr (CPL == 4) {
        d[0] = bflo(v.x); d[1] = bfhi(v.x);
        d[2] = bflo(v.y); d[3] = bfhi(v.y);
    } else {
        d[0] = bflo(v); d[1] = bfhi(v);
    }
}

template <int CPL>
static __device__ __forceinline__ void store_bf16v(unsigned short* p, const float* s) {
    unsigned short tmp[CPL];
#pragma unroll
    for (int c = 0; c < CPL; ++c) tmp[c] = f2bf(s[c]);
    if constexpr (CPL == 8) *(uint4*)p = *(uint4*)tmp;
    else if constexpr (CPL == 4) *(ushort4*)p = *(ushort4*)tmp;
    else if constexpr (CPL == 2) *(ushort2*)p = *(ushort2*)tmp;
    else p[0] = tmp[0];
}

// ---------- DPP group reduction (VALU pipe, not DS) ----------
template <int CTRL>
static __device__ __forceinline__ float dpp_mv(float x) {
    int r = __builtin_amdgcn_update_dpp(0, __builtin_bit_cast(int, x), CTRL, 0xF, 0xF, false);
    return __builtin_bit_cast(float, r);
}
template <int G>
static __device__ __forceinline__ float group_reduce(float x) {
    x += dpp_mv<0xB1>(x);   // xor 1
    x += dpp_mv<0x4E>(x);   // xor 2
    x += dpp_mv<0x124>(x);  // row_ror:4
    x += dpp_mv<0x128>(x);  // row_ror:8 -> 16-lane sum
    if constexpr (G >= 32) x += __shfl_xor(x, 16, 64);
    if constexpr (G >= 64) x += __shfl_xor(x, 32, 64);
    return x;
}

// ---------- merged weight prep: 3 transposed pairs + x->bf16 ----------
static __device__ __forceinline__ void tr_pair(const float* Wa, const float* Wb, int K, int Nn,
                                               unsigned short* Wt, int i) {
    int tot = K * Nn;
    const float* W = (i < tot) ? Wa : Wb;
    unsigned short* dst = Wt + ((i < tot) ? 0 : (size_t)Nn * K);
    int ii = (i < tot) ? i : i - tot;
    int k = ii % K, n = ii / K;
    dst[(size_t)n * K + k] = f2bf(W[(size_t)k * Nn + n]);
}

__global__ void prep_all(const float* __restrict__ x,
                         const float* __restrict__ Wl1, const float* __restrict__ Wr1,
                         const float* __restrict__ Wl2, const float* __restrict__ Wr2,
                         const float* __restrict__ Wlp, const float* __restrict__ Wrp,
                         unsigned short* __restrict__ xbf,
                         unsigned short* __restrict__ wt1, unsigned short* __restrict__ wt2,
                         unsigned short* __restrict__ wt3, int N) {
    const int S1 = 2 * 64 * 1024, S2 = 2 * 1024 * 256, S3 = 2 * 256 * 384;
    int id = blockIdx.x * blockDim.x + threadIdx.x;
    if (id < S1) tr_pair(Wl1, Wr1, 64, 1024, wt1, id);
    else if (id < S1 + S2) tr_pair(Wl2, Wr2, 1024, 256, wt2, id - S1);
    else if (id < S1 + S2 + S3) tr_pair(Wlp, Wrp, 256, 384, wt3, id - S1 - S2);
    else {
        int i = id - S1 - S2 - S3;
        if (i < N * 64) xbf[i] = f2bf(x[i]);
    }
}

// ---------- MFMA bf16 GEMM: C[M,Ntot] = A[M,K] @ Bt[Ntot,K]^T ----------
// Staging via global_load_lds width-16 (m97 ladder step): linear LDS [128][32] bf16,
// wave w stages rows 32w..32w+31 of each tile (2 DMA instrs per tile per wave).
#define GLOAD_LDS16(gp, lp) \
    __builtin_amdgcn_global_load_lds((const __attribute__((address_space(1))) void*)(gp), \
                                     (__attribute__((address_space(3))) void*)(lp), 16, 0, 0)

__global__ __launch_bounds__(256) void gemm_mfma(
    const unsigned short* __restrict__ A, const unsigned short* __restrict__ Bt,
    unsigned short* __restrict__ C, int M, int Ntot, int K) {
    __shared__ unsigned short As[128 * 32];
    __shared__ unsigned short Bs[128 * 32];
    const int tid = threadIdx.x;
    const int m0 = blockIdx.y * 128, n0 = blockIdx.x * 128;
    const int wave = tid >> 6, lane = tid & 63;
    const int wm = (wave >> 1) * 64, wn = (wave & 1) * 64;
    const int r15 = lane & 15, quad = lane >> 4;
    // staging geometry: lane l covers row (l>>2) of a 16-row chunk, 8 elems at col (l&3)*8
    const int srow = lane >> 2, scol = (lane & 3) * 8;
    const int arow0 = m0 + 32 * wave + srow;
    const int brow0 = n0 + 32 * wave + srow;
    const unsigned short* ap0 = A + (size_t)arow0 * K + scol;
    const unsigned short* ap1 = ap0 + (size_t)16 * K;
    const unsigned short* bp0 = Bt + (size_t)brow0 * K + scol;
    const unsigned short* bp1 = bp0 + (size_t)16 * K;
    unsigned short* alds0 = As + (32 * wave) * 32;
    unsigned short* alds1 = alds0 + 16 * 32;
    unsigned short* blds0 = Bs + (32 * wave) * 32;
    unsigned short* blds1 = blds0 + 16 * 32;
    const bool av0 = arow0 < M, av1 = (arow0 + 16) < M;  // OOB rows: stale LDS, C-row guarded at store
    floatx4 acc[4][4];
#pragma unroll
    for (int i = 0; i < 4; ++i)
#pragma unroll
        for (int j = 0; j < 4; ++j) acc[i][j] = (floatx4)0.f;

    for (int k0 = 0; k0 < K; k0 += 32) {
        if (av0) GLOAD_LDS16(ap0, alds0);
        if (av1) GLOAD_LDS16(ap1, alds1);
        GLOAD_LDS16(bp0, blds0);
        GLOAD_LDS16(bp1, blds1);
        ap0 += 32; ap1 += 32; bp0 += 32; bp1 += 32;
        __syncthreads();   // drains vmcnt -> DMA complete
        short8 af[4], bfr[4];
#pragma unroll
        for (int i = 0; i < 4; ++i)
            af[i] = *(const short8*)(&As[(wm + i * 16 + r15) * 32 + quad * 8]);
#pragma unroll
        for (int j = 0; j < 4; ++j)
            bfr[j] = *(const short8*)(&Bs[(wn + j * 16 + r15) * 32 + quad * 8]);
#pragma unroll
        for (int i = 0; i < 4; ++i)
#pragma unroll
            for (int j = 0; j < 4; ++j)
                acc[i][j] = __builtin_amdgcn_mfma_f32_16x16x32_bf16(af[i], bfr[j], acc[i][j], 0, 0, 0);
        __syncthreads();
    }
#pragma unroll
    for (int i = 0; i < 4; ++i)
#pragma unroll
        for (int j = 0; j < 4; ++j)
#pragma unroll
            for (int r = 0; r < 4; ++r) {
                int m = m0 + wm + i * 16 + quad * 4 + r;
                int n = n0 + wn + j * 16 + r15;
                if (m < M) C[(size_t)m * Ntot + n] = f2bf(acc[i][j][r]);
            }
}

// ---------- CSR build for BOTH graphs ----------
__global__ void count2_kernel(const int* __restrict__ dst0, const int* __restrict__ dst1,
                              int E, int N, int* __restrict__ cnt) {
    int e = blockIdx.x * blockDim.x + threadIdx.x;
    if (e < E) atomicAdd(&cnt[dst0[e]], 1);
    else if (e < 2 * E) atomicAdd(&cnt[N + dst1[e - E]], 1);
}

__global__ __launch_bounds__(1024) void scan_kernel(const int* __restrict__ cnt_all, int N,
                                                    int* __restrict__ off_all, int* __restrict__ cur_all) {
    const int* cnt = cnt_all + blockIdx.x * N;
    int* off = off_all + blockIdx.x * (N + 1);
    int* cur = cur_all + blockIdx.x * N;
    __shared__ int part[1024];
    int t = threadIdx.x;
    int per = (N + 1023) >> 10;
    int base = t * per;
    int s = 0;
    for (int i = 0; i < per; ++i) { int idx = base + i; if (idx < N) s += cnt[idx]; }
    part[t] = s;
    __syncthreads();
    for (int d2 = 1; d2 < 1024; d2 <<= 1) {
        int v = (t >= d2) ? part[t - d2] : 0;
        __syncthreads();
        part[t] += v;
        __syncthreads();
    }
    int pre = (t == 0) ? 0 : part[t - 1];
    for (int i = 0; i < per; ++i) {
        int idx = base + i;
        if (idx < N) { off[idx] = pre; cur[idx] = pre; pre += cnt[idx]; }
    }
    if (t == 1023) off[N] = part[1023];
}

// graph0: writes int2 edges (src, orig_e) for the ea-gather + srcs[]; graph1: srcs only
__global__ void fill2_kernel(const int* __restrict__ src0, const int* __restrict__ dst0,
                             const int* __restrict__ src1, const int* __restrict__ dst1,
                             int E, int N, int* __restrict__ cur, int2* __restrict__ edges,
                             int* __restrict__ srcs) {
    int e = blockIdx.x * blockDim.x + threadIdx.x;
    if (e < E) {
        int p = atomicAdd(&cur[dst0[e]], 1);
        edges[p] = make_int2(src0[e], e);
        srcs[p] = src0[e];
    } else if (e < 2 * E) {
        int i = e - E;
        int p = atomicAdd(&cur[N + dst1[i]], 1);
        srcs[E + p] = src1[i];
    }
}

// ---------- ea gather into CSR order: ead[j][0..7] = ea[edges[j].y][0..7] ----------
__global__ void ea_gather_kernel(const float* __restrict__ ea, const int2* __restrict__ edges,
                                 float* __restrict__ ead, int E) {
    int j = blockIdx.x * blockDim.x + threadIdx.x;
    if (j >= E) return;
    int ey = edges[j].y;
    const float4* s = (const float4*)(ea + (size_t)ey * 8);
    float4* o = (float4*)(ead + (size_t)j * 8);
    o[0] = s[0];
    o[1] = s[1];
}

// ---------- staged edge group (software pipeline buffer) ----------
template <int CPL, int NE>
struct EStage {
    int src[NE];
    typename RawT<CPL>::T xv[NE];
};

template <int D, int CPL, int NE>
static __device__ __forceinline__ void stage_x(
    const unsigned short* __restrict__ xlr, const int* __restrict__ srcs,
    int j, int c0, EStage<CPL, NE>& s) {
#pragma unroll
    for (int n = 0; n < NE; ++n) s.src[n] = srcs[j + n];
#pragma unroll
    for (int n = 0; n < NE; ++n)
        s.xv[n] = *(const typename RawT<CPL>::T*)(xlr + (size_t)s.src[n] * (2 * D) + c0);
}

// ---------- fused attention (HASE) compute: scalar fp32 FMA, exp2-domain softmax ----------
template <int D, int CPL, int QP, int G, int NE>
static __device__ __forceinline__ void hase_compute(
    const EStage<CPL, NE>& s, const float* __restrict__ ead, int j,
    const float* wb, const float (&att_r)[CPL], const float (&xr_r)[CPL],
    float& m, float& l, float (&acc)[CPL]) {
    float4 evr[NE][2];
#pragma unroll
    for (int n = 0; n < NE; ++n) {
        const float4* q = (const float4*)(ead + (size_t)(j + n) * 8);
        evr[n][0] = q[0];
        evr[n][1] = q[1];
    }
    float z[NE][CPL];
#pragma unroll
    for (int n = 0; n < NE; ++n) {
        float xv[CPL];
        unpackx<CPL>(s.xv[n], xv);
#pragma unroll
        for (int c = 0; c < CPL; ++c) z[n][c] = xv[c] + xr_r[c];
    }
#pragma unroll
    for (int k = 0; k < 8; ++k) {
#pragma unroll
        for (int q = 0; q < CPL / 4; ++q) {
            float4 w4 = *(const float4*)(wb + k * D + q * QP);
#pragma unroll
            for (int n = 0; n < NE; ++n) {
                float ek = f4get(evr[n][k >> 2], k & 3);
                z[n][q * 4 + 0] = fmaf(ek, w4.x, z[n][q * 4 + 0]);
                z[n][q * 4 + 1] = fmaf(ek, w4.y, z[n][q * 4 + 1]);
                z[n][q * 4 + 2] = fmaf(ek, w4.z, z[n][q * 4 + 2]);
                z[n][q * 4 + 3] = fmaf(ek, w4.w, z[n][q * 4 + 3]);
            }
        }
    }
    float lg[NE];
#pragma unroll
    for (int n = 0; n < NE; ++n) {
        float t = 0.f;
#pragma unroll
        for (int c = 0; c < CPL; ++c) {
            float a = z[n][c] > 0.f ? z[n][c] : 0.2f * z[n][c];
            t = fmaf(att_r[c], a, t);
        }
        lg[n] = group_reduce<G>(t);
    }
    float mn = m;
#pragma unroll
    for (int n = 0; n < NE; ++n) mn = fmaxf(mn, lg[n]);
    float sc = fexp2(m - mn);
    float p[NE], ps = 0.f;
#pragma unroll
    for (int n = 0; n < NE; ++n) { p[n] = fexp2(lg[n] - mn); ps += p[n]; }
    m = mn;
    l = fmaf(l, sc, ps);
#pragma unroll
    for (int c = 0; c < CPL; ++c) acc[c] *= sc;
#pragma unroll
    for (int n = 0; n < NE; ++n) {
        float xv[CPL];
        unpackx<CPL>(s.xv[n], xv);   // re-unpack: trades ~CPL ops for NE*CPL fewer live VGPRs
#pragma unroll
        for (int c = 0; c < CPL; ++c) acc[c] = fmaf(p[n], xv[c], acc[c]);
    }
}

template <int D, int C, int CB, int WPN, bool RELU>
__global__ __launch_bounds__(256) void attn_hase(
    const unsigned short* __restrict__ xlr, const float* __restrict__ ead,
    const float* __restrict__ We, const float* __restrict__ att,
    const int* __restrict__ srcs, const int* __restrict__ off,
    const float* __restrict__ bias, unsigned short* __restrict__ outp, int N) {
    constexpr int CPL = CB / 64;
    constexpr int HW = CB / C;
    constexpr int G = 64 / HW;
    constexpr int NPB = 4 / WPN;
    constexpr int QP = CB * 4 / CPL;
    __shared__ float wsh[8 * D];
    for (int f4 = threadIdx.x; f4 < 2 * D; f4 += 256) {
        int k = f4 / (D / 4);
        int c = (f4 - k * (D / 4)) * 4;
        int b = c / CB, cc = c - b * CB;
        int ln = cc / CPL, q = (cc % CPL) / 4;
        int dst = k * (D / 4) + (b * CB + q * QP + ln * 4) / 4;
        ((float4*)wsh)[dst] = ((const float4*)We)[f4];
    }
    __syncthreads();

    const int wid = threadIdx.x >> 6, lane = threadIdx.x & 63;
    const int wv = wid % WPN, wn = wid / WPN;
    const int c0 = wv * CB + lane * CPL;
    const float* wb = wsh + wv * CB + lane * 4;

    const float L2E = 1.4426950408889634f;   // exp2-domain softmax
    float att_r[CPL];
#pragma unroll
    for (int c = 0; c < CPL; ++c) att_r[c] = att[c0 + c] * L2E;

    for (int node = blockIdx.x * NPB + wn; node < N; node += gridDim.x * NPB) {
        typename RawT<CPL>::T xrw =
            *(const typename RawT<CPL>::T*)(xlr + (size_t)node * (2 * D) + D + c0);
        float xr_r[CPL];
        unpackx<CPL>(xrw, xr_r);
        float m = -1e30f, l = 0.f, acc[CPL];
#pragma unroll
        for (int c = 0; c < CPL; ++c) acc[c] = 0.f;

        const int jb = __builtin_amdgcn_readfirstlane(off[node]);
        const int je = __builtin_amdgcn_readfirstlane(off[node + 1]);
        int j = jb;
        int g = (je - jb) >> 2;
        // two-stage software pipeline: group g+1 gathers in flight under group g compute
        if (g > 0) {
            EStage<CPL, 4> A, B;
            stage_x<D, CPL, 4>(xlr, srcs, j, c0, A);
            while (g >= 2) {
                stage_x<D, CPL, 4>(xlr, srcs, j + 4, c0, B);
                hase_compute<D, CPL, QP, G, 4>(A, ead, j, wb, att_r, xr_r, m, l, acc);
                j += 4; --g;
                if (g >= 2) {
                    stage_x<D, CPL, 4>(xlr, srcs, j + 4, c0, A);
                    hase_compute<D, CPL, QP, G, 4>(B, ead, j, wb, att_r, xr_r, m, l, acc);
                    j += 4; --g;
                } else if (g == 1) {
                    hase_compute<D, CPL, QP, G, 4>(B, ead, j, wb, att_r, xr_r, m, l, acc);
                    j += 4; --g;
                }
            }
            if (g == 1) {
                hase_compute<D, CPL, QP, G, 4>(A, ead, j, wb, att_r, xr_r, m, l, acc);
                j += 4;
            }
        }
        for (; j < je; ++j) {
            EStage<CPL, 1> S;
            stage_x<D, CPL, 1>(xlr, srcs, j, c0, S);
            hase_compute<D, CPL, QP, G, 1>(S, ead, j, wb, att_r, xr_r, m, l, acc);
        }

        float inv = 1.f / (l + 1e-16f);
        float r[CPL];
#pragma unroll
        for (int c = 0; c < CPL; ++c) {
            r[c] = fmaf(acc[c], inv, bias[c0 + c]);
            if constexpr (RELU) r[c] = fmaxf(r[c], 0.f);
        }
        store_bf16v<CPL>(outp + (size_t)node * D + c0, r);
    }
}

// ---------- fused attention, no edge_attr (layer 3) ----------
template <int D, int CPL, int G, int NE>
static __device__ __forceinline__ void noe_compute(
    const EStage<CPL, NE>& s,
    const float (&att_r)[CPL], const float (&xr_r)[CPL],
    float& m, float& l, float (&acc)[CPL]) {
    float xv[NE][CPL], lg[NE];
#pragma unroll
    for (int n = 0; n < NE; ++n) unpackx<CPL>(s.xv[n], xv[n]);
#pragma unroll
    for (int n = 0; n < NE; ++n) {
        float t = 0.f;
#pragma unroll
        for (int c = 0; c < CPL; ++c) {
            float z = xv[n][c] + xr_r[c];
            z = z > 0.f ? z : 0.2f * z;
            t = fmaf(att_r[c], z, t);
        }
        lg[n] = group_reduce<G>(t);
    }
    float mn = m;
#pragma unroll
    for (int n = 0; n < NE; ++n) mn = fmaxf(mn, lg[n]);
    float sc = fexp2(m - mn);
    float p[NE], ps = 0.f;
#pragma unroll
    for (int n = 0; n < NE; ++n) { p[n] = fexp2(lg[n] - mn); ps += p[n]; }
    m = mn;
    l = fmaf(l, sc, ps);
#pragma unroll
    for (int c = 0; c < CPL; ++c) {
        float t = p[0] * xv[0][c];
#pragma unroll
        for (int n = 1; n < NE; ++n) t = fmaf(p[n], xv[n][c], t);
        acc[c] = fmaf(acc[c], sc, t);
    }
}

template <int D, int C, int CB, bool RELU>
static __device__ __forceinline__ void attn_wave3(
    const unsigned short* __restrict__ xlr, const float* __restrict__ att,
    const int* __restrict__ srcs, int jb, int je,
    const float* __restrict__ bias, float* __restrict__ outp,
    int node, int cb, int lane) {
    constexpr int CPL = CB / 64;
    constexpr int HW = CB / C;
    constexpr int G = 64 / HW;
    const int c0 = cb + lane * CPL;
    const float L2E = 1.4426950408889634f;

    typename RawT<CPL>::T xrw =
        *(const typename RawT<CPL>::T*)(xlr + (size_t)node * (2 * D) + D + c0);
    float xr_r[CPL], att_r[CPL];
    unpackx<CPL>(xrw, xr_r);
#pragma unroll
    for (int c = 0; c < CPL; ++c) att_r[c] = att[c0 + c] * L2E;

    float m = -1e30f, l = 0.f, acc[CPL];
#pragma unroll
    for (int c = 0; c < CPL; ++c) acc[c] = 0.f;

    int j = jb;
    int g = (je - jb) >> 2;
    if (g > 0) {
        EStage<CPL, 4> A, B;
        stage_x<D, CPL, 4>(xlr, srcs, j, c0, A);
        while (g >= 2) {
            stage_x<D, CPL, 4>(xlr, srcs, j + 4, c0, B);
            noe_compute<D, CPL, G, 4>(A, att_r, xr_r, m, l, acc);
            j += 4; --g;
            if (g >= 2) {
                stage_x<D, CPL, 4>(xlr, srcs, j + 4, c0, A);
                noe_compute<D, CPL, G, 4>(B, att_r, xr_r, m, l, acc);
                j += 4; --g;
            } else if (g == 1) {
                noe_compute<D, CPL, G, 4>(B, att_r, xr_r, m, l, acc);
                j += 4; --g;
            }
        }
        if (g == 1) {
            noe_compute<D, CPL, G, 4>(A, att_r, xr_r, m, l, acc);
            j += 4;
        }
    }
    for (; j < je; ++j) {
        EStage<CPL, 1> S;
        stage_x<D, CPL, 1>(xlr, srcs, j, c0, S);
        noe_compute<D, CPL, G, 1>(S, att_r, xr_r, m, l, acc);
    }

    float inv = 1.f / (l + 1e-16f);
    float* out = outp + (size_t)node * D + c0;
    float tmp[CPL];
#pragma unroll
    for (int c = 0; c < CPL; ++c) {
        float r = fmaf(acc[c], inv, bias[c0 + c]);
        if constexpr (RELU) r = fmaxf(r, 0.f);
        tmp[c] = r;
    }
    if constexpr (CPL == 4) *(float4*)out = *(float4*)tmp;
    else if constexpr (CPL == 2) *(float2*)out = *(float2*)tmp;
    else out[0] = tmp[0];
}

template <int D, int C, int CB0, int CB1, bool RELU>
__global__ __launch_bounds__(256) void attn_noe(
    const unsigned short* __restrict__ xlr, const float* __restrict__ att,
    const int* __restrict__ srcs, const int* __restrict__ off,
    const float* __restrict__ bias, float* __restrict__ outp, int N) {
    const int wid = threadIdx.x >> 6, lane = threadIdx.x & 63;
    const int gw = blockIdx.x * 4 + wid;
    const int node = gw >> 1, wv = gw & 1;
    if (node >= N) return;
    const int jb = __builtin_amdgcn_readfirstlane(off[node]);
    const int je = __builtin_amdgcn_readfirstlane(off[node + 1]);
    if (wv == 0)
        attn_wave3<D, C, CB0, RELU>(xlr, att, srcs, jb, je, bias, outp, node, 0, lane);
    else
        attn_wave3<D, C, CB1, RELU>(xlr, att, srcs, jb, je, bias, outp, node, CB0, lane);
}

// ---------- head: 2-layer MLP on master (last) node of each graph ----------
__global__ void mlp_kernel(const float* __restrict__ h3, const int* __restrict__ nn,
                           const float* __restrict__ Wfc1, const float* __restrict__ bfc1,
                           const float* __restrict__ Wfc2, const float* __restrict__ bfc2,
                           float* __restrict__ out, int G) {
    int g = blockIdx.x, t = threadIdx.x;  // 64 threads
    int s = 0;
    for (int k = 0; k <= g; ++k) s += nn[k];
    const float* row = h3 + (size_t)(s - 1) * 384;
    float z = bfc1[t];
    for (int k = 0; k < 384; ++k) z = fmaf(row[k], Wfc1[k * 64 + t], z);
    z = fmaxf(z, 0.f);
    float v = z * Wfc2[t];
#pragma unroll
    for (int o = 32; o; o >>= 1) v += __shfl_xor(v, o, 64);
    if (t == 0) out[g] = v + bfc2[0];
}

extern "C" void kernel_launch(void* const* d_in, const int* in_sizes, int n_in,
                              void* d_out, int out_size, void* d_ws, size_t ws_size,
                              hipStream_t stream) {
    const float* x    = (const float*)d_in[0];
    const float* ea   = (const float*)d_in[1];
    const float* Wl1  = (const float*)d_in[2];
    const float* Wr1  = (const float*)d_in[3];
    const float* We1  = (const float*)d_in[4];
    const float* att1 = (const float*)d_in[5];
    const float* b1   = (const float*)d_in[6];
    const float* Wl2  = (const float*)d_in[7];
    const float* Wr2  = (const float*)d_in[8];
    const float* We2  = (const float*)d_in[9];
    const float* att2 = (const float*)d_in[10];
    const float* b2   = (const float*)d_in[11];
    const float* Wlp  = (const float*)d_in[12];
    const float* Wrp  = (const float*)d_in[13];
    const float* attp = (const float*)d_in[14];
    const float* bp   = (const float*)d_in[15];
    const float* Wfc1 = (const float*)d_in[16];
    const float* bfc1 = (const float*)d_in[17];
    const float* Wfc2 = (const float*)d_in[18];
    const float* bfc2 = (const float*)d_in[19];
    const int* ei     = (const int*)d_in[20];
    const int* eim    = (const int*)d_in[21];
    const int* nn     = (const int*)d_in[22];

    const int N = in_sizes[0] / 64;   // 20000
    const int E = in_sizes[20] / 2;   // 160000
    const int G = in_sizes[22];       // 100
    const int* src1 = ei,  *dst1 = ei + E;
    const int* srcm = eim, *dstm = eim + E;

    // ---- workspace layout (~160 MB peak, unchanged footprint) ----
    char* w = (char*)d_ws;
    size_t o = 0;
    auto alloc = [&](size_t b) { size_t r = o; o += (b + 255) & ~(size_t)255; return r; };
    char* R1 = w + alloc((size_t)N * 2048 * 2);
    unsigned short* xlr1 = (unsigned short*)R1;
    unsigned short* xlr3 = (unsigned short*)R1;
    float* h3 = (float*)(R1 + (size_t)N * 768 * 2 + 256);
    unsigned short* h1   = (unsigned short*)(w + alloc((size_t)N * 1024 * 2));
    unsigned short* xlr2 = (unsigned short*)(w + alloc((size_t)N * 512 * 2));
    unsigned short* h2   = (unsigned short*)(w + alloc((size_t)N * 256 * 2));
    unsigned short* xbf  = (unsigned short*)(w + alloc((size_t)N * 64 * 2));
    unsigned short* wt1  = (unsigned short*)(w + alloc((size_t)2048 * 64 * 2));
    unsigned short* wt2  = (unsigned short*)(w + alloc((size_t)512 * 1024 * 2));
    unsigned short* wt3  = (unsigned short*)(w + alloc((size_t)768 * 256 * 2));
    int*  cnt   = (int*)(w + alloc((size_t)2 * N * 4));
    int*  off   = (int*)(w + alloc((size_t)2 * (N + 1) * 4));
    int*  cur   = (int*)(w + alloc((size_t)2 * N * 4));
    // edge region: [E int2 edges(graph0)] [2E int srcs]
    char* eReg  = w + alloc((size_t)2 * E * 8 + 4096);
    int2* edges = (int2*)eReg;
    int*  srcs  = (int*)(eReg + (size_t)E * 8);
    (void)ws_size; (void)n_in; (void)out_size;

    // ead buffers live in DEAD regions (zero extra footprint):
    //   ead1 @ xlr2 region: free until gemm2 writes xlr2 (after attn1 done)
    //   ead2 @ h1 region:   free after gemm2 consumed h1 (before attn2)
    float* ead1 = (float*)xlr2;   // E*8*4 = 5.12 MB <= 20.48 MB
    float* ead2 = (float*)h1;     // 5.12 MB <= 40.96 MB

    dim3 blk(256);

    // ---- weight prep (single merged launch) ----
    {
        int tot = 2 * 64 * 1024 + 2 * 1024 * 256 + 2 * 256 * 384 + N * 64;
        prep_all<<<DIV_UP(tot, 256), blk, 0, stream>>>(x, Wl1, Wr1, Wl2, Wr2, Wlp, Wrp,
                                                       xbf, wt1, wt2, wt3, N);
    }

    // ---- CSR for both graphs ----
    hipMemsetAsync(cnt, 0, (size_t)2 * N * 4, stream);
    count2_kernel<<<DIV_UP(2 * E, 256), blk, 0, stream>>>(dst1, dstm, E, N, cnt);
    scan_kernel<<<2, 1024, 0, stream>>>(cnt, N, off, cur);
    fill2_kernel<<<DIV_UP(2 * E, 256), blk, 0, stream>>>(src1, dst1, srcm, dstm, E, N, cur,
                                                         edges, srcs);
    ea_gather_kernel<<<DIV_UP(E, 256), blk, 0, stream>>>(ea, edges, ead1, E);
    const int* off3 = off + (N + 1);
    const int* srcs3 = srcs + E;

    // ---- Layer 1: H=4, C=256, D=1024 — 2 waves/node, CPL=8, G=32 ----
    gemm_mfma<<<dim3(2048 / 128, DIV_UP(N, 128)), blk, 0, stream>>>(xbf, wt1, xlr1, N, 2048, 64);
    attn_hase<1024, 256, 512, 2, true><<<2560, blk, 0, stream>>>(
        xlr1, ead1, We1, att1, srcs, off, b1, h1, N);

    // ---- Layer 2: H=4, C=64, D=256 — 1 wave/node, CPL=4, G=16 ----
    gemm_mfma<<<dim3(512 / 128, DIV_UP(N, 128)), blk, 0, stream>>>(h1, wt2, xlr2, N, 512, 1024);
    ea_gather_kernel<<<DIV_UP(E, 256), blk, 0, stream>>>(ea, edges, ead2, E);
    attn_hase<256, 64, 256, 1, true><<<1280, blk, 0, stream>>>(
        xlr2, ead2, We2, att2, srcs, off, b2, h2, N);

    // ---- Layer 3: H=6, C=64, D=384 — 2 waves/node (roles 256/128), fp32 out ----
    gemm_mfma<<<dim3(768 / 128, DIV_UP(N, 128)), blk, 0, stream>>>(h2, wt3, xlr3, N, 768, 256);
    attn_noe<384, 64, 256, 128, false><<<DIV_UP(N, 2), blk, 0, stream>>>(
        xlr3, attp, srcs3, off3, bp, h3, N);

    // ---- head ----
    mlp_kernel<<<G, 64, 0, stream>>>(h3, nn, Wfc1, bfc1, Wfc2, bfc2, (float*)d_out, G);
}

// Round 4
// 415.344 us; speedup vs baseline: 1.0981x; 1.0981x over previous
//
#include <hip/hip_runtime.h>
#include <hip/hip_bf16.h>

#define DIV_UP(a,b) (((a)+(b)-1)/(b))

typedef __attribute__((ext_vector_type(8))) short short8;
typedef __attribute__((ext_vector_type(4))) float floatx4;
typedef _Float16 half2t __attribute__((ext_vector_type(2)));

// ---------- bf16 helpers (manual, deterministic RNE) ----------
static __device__ __forceinline__ unsigned short f2bf(float v) {
    unsigned u = __builtin_bit_cast(unsigned, v);
    u += 0x7fffu + ((u >> 16) & 1u);
    return (unsigned short)(u >> 16);
}
static __device__ __forceinline__ float bflo(unsigned v) {
    return __builtin_bit_cast(float, v << 16);
}
static __device__ __forceinline__ float bfhi(unsigned v) {
    return __builtin_bit_cast(float, v & 0xffff0000u);
}
static __device__ __forceinline__ float fexp2(float x) { return __builtin_amdgcn_exp2f(x); }

// f16 pack + dot2: v_dot2_f32_f16 = 2 f16 FMAs/instr, f32 accumulate (full-rate)
static __device__ __forceinline__ unsigned packh2(float lo, float hi) {
    half2t h; h[0] = (_Float16)lo; h[1] = (_Float16)hi;
    return __builtin_bit_cast(unsigned, h);
}
static __device__ __forceinline__ float fdot2(unsigned a, unsigned b, float c) {
    return __builtin_amdgcn_fdot2(__builtin_bit_cast(half2t, a),
                                  __builtin_bit_cast(half2t, b), c, false);
}
static __device__ __forceinline__ unsigned uget(const uint4 v, int k) {
    return k == 0 ? v.x : k == 1 ? v.y : k == 2 ? v.z : v.w;
}

// raw per-lane x-row slice type by channels-per-lane
template <int CPL> struct RawT;
template <> struct RawT<8> { using T = uint4; };
template <> struct RawT<4> { using T = uint2; };
template <> struct RawT<2> { using T = unsigned; };

template <int CPL>
static __device__ __forceinline__ void unpackx(const typename RawT<CPL>::T& v, float* d) {
    if constexpr (CPL == 8) {
        d[0] = bflo(v.x); d[1] = bfhi(v.x);
        d[2] = bflo(v.y); d[3] = bfhi(v.y);
        d[4] = bflo(v.z); d[5] = bfhi(v.z);
        d[6] = bflo(v.w); d[7] = bfhi(v.w);
    } else if constexpr (CPL == 4) {
        d[0] = bflo(v.x); d[1] = bfhi(v.x);
        d[2] = bflo(v.y); d[3] = bfhi(v.y);
    } else {
        d[0] = bflo(v); d[1] = bfhi(v);
    }
}

template <int CPL>
static __device__ __forceinline__ void store_bf16v(unsigned short* p, const float* s) {
    unsigned short tmp[CPL];
#pragma unroll
    for (int c = 0; c < CPL; ++c) tmp[c] = f2bf(s[c]);
    if constexpr (CPL == 8) *(uint4*)p = *(uint4*)tmp;
    else if constexpr (CPL == 4) *(ushort4*)p = *(ushort4*)tmp;
    else if constexpr (CPL == 2) *(ushort2*)p = *(ushort2*)tmp;
    else p[0] = tmp[0];
}

// ---------- DPP group reduction (VALU pipe, not DS) ----------
template <int CTRL>
static __device__ __forceinline__ float dpp_mv(float x) {
    int r = __builtin_amdgcn_update_dpp(0, __builtin_bit_cast(int, x), CTRL, 0xF, 0xF, false);
    return __builtin_bit_cast(float, r);
}
template <int G>
static __device__ __forceinline__ float group_reduce(float x) {
    x += dpp_mv<0xB1>(x);   // xor 1
    x += dpp_mv<0x4E>(x);   // xor 2
    x += dpp_mv<0x124>(x);  // row_ror:4
    x += dpp_mv<0x128>(x);  // row_ror:8 -> 16-lane sum
    if constexpr (G >= 32) x += __shfl_xor(x, 16, 64);
    if constexpr (G >= 64) x += __shfl_xor(x, 32, 64);
    return x;
}

// ---------- merged weight prep: 3 transposed pairs + x->bf16 ----------
static __device__ __forceinline__ void tr_pair(const float* Wa, const float* Wb, int K, int Nn,
                                               unsigned short* Wt, int i) {
    int tot = K * Nn;
    const float* W = (i < tot) ? Wa : Wb;
    unsigned short* dst = Wt + ((i < tot) ? 0 : (size_t)Nn * K);
    int ii = (i < tot) ? i : i - tot;
    int k = ii % K, n = ii / K;
    dst[(size_t)n * K + k] = f2bf(W[(size_t)k * Nn + n]);
}

__global__ void prep_all(const float* __restrict__ x,
                         const float* __restrict__ Wl1, const float* __restrict__ Wr1,
                         const float* __restrict__ Wl2, const float* __restrict__ Wr2,
                         const float* __restrict__ Wlp, const float* __restrict__ Wrp,
                         unsigned short* __restrict__ xbf,
                         unsigned short* __restrict__ wt1, unsigned short* __restrict__ wt2,
                         unsigned short* __restrict__ wt3, int N) {
    const int S1 = 2 * 64 * 1024, S2 = 2 * 1024 * 256, S3 = 2 * 256 * 384;
    int id = blockIdx.x * blockDim.x + threadIdx.x;
    if (id < S1) tr_pair(Wl1, Wr1, 64, 1024, wt1, id);
    else if (id < S1 + S2) tr_pair(Wl2, Wr2, 1024, 256, wt2, id - S1);
    else if (id < S1 + S2 + S3) tr_pair(Wlp, Wrp, 256, 384, wt3, id - S1 - S2);
    else {
        int i = id - S1 - S2 - S3;
        if (i < N * 64) xbf[i] = f2bf(x[i]);
    }
}

// ---------- MFMA bf16 GEMM: C[M,Ntot] = A[M,K] @ Bt[Ntot,K]^T ----------
#define GLOAD_LDS16(gp, lp) \
    __builtin_amdgcn_global_load_lds((const __attribute__((address_space(1))) void*)(gp), \
                                     (__attribute__((address_space(3))) void*)(lp), 16, 0, 0)

__global__ __launch_bounds__(256) void gemm_mfma(
    const unsigned short* __restrict__ A, const unsigned short* __restrict__ Bt,
    unsigned short* __restrict__ C, int M, int Ntot, int K) {
    __shared__ unsigned short As[128 * 32];
    __shared__ unsigned short Bs[128 * 32];
    const int tid = threadIdx.x;
    const int m0 = blockIdx.y * 128, n0 = blockIdx.x * 128;
    const int wave = tid >> 6, lane = tid & 63;
    const int wm = (wave >> 1) * 64, wn = (wave & 1) * 64;
    const int r15 = lane & 15, quad = lane >> 4;
    const int srow = lane >> 2, scol = (lane & 3) * 8;
    const int arow0 = m0 + 32 * wave + srow;
    const int brow0 = n0 + 32 * wave + srow;
    const unsigned short* ap0 = A + (size_t)arow0 * K + scol;
    const unsigned short* ap1 = ap0 + (size_t)16 * K;
    const unsigned short* bp0 = Bt + (size_t)brow0 * K + scol;
    const unsigned short* bp1 = bp0 + (size_t)16 * K;
    unsigned short* alds0 = As + (32 * wave) * 32;
    unsigned short* alds1 = alds0 + 16 * 32;
    unsigned short* blds0 = Bs + (32 * wave) * 32;
    unsigned short* blds1 = blds0 + 16 * 32;
    const bool av0 = arow0 < M, av1 = (arow0 + 16) < M;
    floatx4 acc[4][4];
#pragma unroll
    for (int i = 0; i < 4; ++i)
#pragma unroll
        for (int j = 0; j < 4; ++j) acc[i][j] = (floatx4)0.f;

    for (int k0 = 0; k0 < K; k0 += 32) {
        if (av0) GLOAD_LDS16(ap0, alds0);
        if (av1) GLOAD_LDS16(ap1, alds1);
        GLOAD_LDS16(bp0, blds0);
        GLOAD_LDS16(bp1, blds1);
        ap0 += 32; ap1 += 32; bp0 += 32; bp1 += 32;
        __syncthreads();
        short8 af[4], bfr[4];
#pragma unroll
        for (int i = 0; i < 4; ++i)
            af[i] = *(const short8*)(&As[(wm + i * 16 + r15) * 32 + quad * 8]);
#pragma unroll
        for (int j = 0; j < 4; ++j)
            bfr[j] = *(const short8*)(&Bs[(wn + j * 16 + r15) * 32 + quad * 8]);
#pragma unroll
        for (int i = 0; i < 4; ++i)
#pragma unroll
            for (int j = 0; j < 4; ++j)
                acc[i][j] = __builtin_amdgcn_mfma_f32_16x16x32_bf16(af[i], bfr[j], acc[i][j], 0, 0, 0);
        __syncthreads();
    }
#pragma unroll
    for (int i = 0; i < 4; ++i)
#pragma unroll
        for (int j = 0; j < 4; ++j)
#pragma unroll
            for (int r = 0; r < 4; ++r) {
                int m = m0 + wm + i * 16 + quad * 4 + r;
                int n = n0 + wn + j * 16 + r15;
                if (m < M) C[(size_t)m * Ntot + n] = f2bf(acc[i][j][r]);
            }
}

// ---------- CSR build for BOTH graphs ----------
__global__ void count2_kernel(const int* __restrict__ dst0, const int* __restrict__ dst1,
                              int E, int N, int* __restrict__ cnt) {
    int e = blockIdx.x * blockDim.x + threadIdx.x;
    if (e < E) atomicAdd(&cnt[dst0[e]], 1);
    else if (e < 2 * E) atomicAdd(&cnt[N + dst1[e - E]], 1);
}

__global__ __launch_bounds__(1024) void scan_kernel(const int* __restrict__ cnt_all, int N,
                                                    int* __restrict__ off_all, int* __restrict__ cur_all) {
    const int* cnt = cnt_all + blockIdx.x * N;
    int* off = off_all + blockIdx.x * (N + 1);
    int* cur = cur_all + blockIdx.x * N;
    __shared__ int part[1024];
    int t = threadIdx.x;
    int per = (N + 1023) >> 10;
    int base = t * per;
    int s = 0;
    for (int i = 0; i < per; ++i) { int idx = base + i; if (idx < N) s += cnt[idx]; }
    part[t] = s;
    __syncthreads();
    for (int d2 = 1; d2 < 1024; d2 <<= 1) {
        int v = (t >= d2) ? part[t - d2] : 0;
        __syncthreads();
        part[t] += v;
        __syncthreads();
    }
    int pre = (t == 0) ? 0 : part[t - 1];
    for (int i = 0; i < per; ++i) {
        int idx = base + i;
        if (idx < N) { off[idx] = pre; cur[idx] = pre; pre += cnt[idx]; }
    }
    if (t == 1023) off[N] = part[1023];
}

__global__ void fill2_kernel(const int* __restrict__ src0, const int* __restrict__ dst0,
                             const int* __restrict__ src1, const int* __restrict__ dst1,
                             int E, int N, int* __restrict__ cur, int2* __restrict__ edges,
                             int* __restrict__ srcs) {
    int e = blockIdx.x * blockDim.x + threadIdx.x;
    if (e < E) {
        int p = atomicAdd(&cur[dst0[e]], 1);
        edges[p] = make_int2(src0[e], e);
        srcs[p] = src0[e];
    } else if (e < 2 * E) {
        int i = e - E;
        int p = atomicAdd(&cur[N + dst1[i]], 1);
        srcs[E + p] = src1[i];
    }
}

// ---------- ea gather into CSR order, packed f16 pairs: 16 B/edge ----------
__global__ void ea_gather_kernel(const float* __restrict__ ea, const int2* __restrict__ edges,
                                 uint4* __restrict__ ead, int E) {
    int j = blockIdx.x * blockDim.x + threadIdx.x;
    if (j >= E) return;
    int ey = edges[j].y;
    const float4* s = (const float4*)(ea + (size_t)ey * 8);
    float4 a = s[0], b = s[1];
    uint4 o;
    o.x = packh2(a.x, a.y);
    o.y = packh2(a.z, a.w);
    o.z = packh2(b.x, b.y);
    o.w = packh2(b.z, b.w);
    ead[j] = o;
}

// ---------- fused attention (HASE): dot2 We-matvec, exp2 softmax ----------
template <int D, int CPL, int G, int NE>
static __device__ __forceinline__ void hase_group(
    const unsigned short* __restrict__ xlr, const uint4* __restrict__ ej,
    const int* __restrict__ sj, const unsigned* wbu,
    const float (&att_r)[CPL], const float (&xr_r)[CPL], int c0,
    float& m, float& l, float (&acc)[CPL]) {
    int src[NE];
#pragma unroll
    for (int n = 0; n < NE; ++n) src[n] = sj[n];
    uint4 ev[NE];
#pragma unroll
    for (int n = 0; n < NE; ++n) ev[n] = ej[n];
    float xv[NE][CPL], z[NE][CPL];
#pragma unroll
    for (int n = 0; n < NE; ++n) {
        typename RawT<CPL>::T xw =
            *(const typename RawT<CPL>::T*)(xlr + (size_t)src[n] * (2 * D) + c0);
        unpackx<CPL>(xw, xv[n]);
#pragma unroll
        for (int c = 0; c < CPL; ++c) z[n][c] = xv[n][c] + xr_r[c];
    }
    // We-matvec: 4 k-pairs x dot2 (f16 inputs, f32 accumulate)
#pragma unroll
    for (int kp = 0; kp < 4; ++kp) {
#pragma unroll
        for (int q = 0; q < CPL / 4; ++q) {
            uint4 w4 = *(const uint4*)(wbu + kp * D + q * 256);
#pragma unroll
            for (int n = 0; n < NE; ++n) {
                unsigned ep = uget(ev[n], kp);
                z[n][q * 4 + 0] = fdot2(ep, w4.x, z[n][q * 4 + 0]);
                z[n][q * 4 + 1] = fdot2(ep, w4.y, z[n][q * 4 + 1]);
                z[n][q * 4 + 2] = fdot2(ep, w4.z, z[n][q * 4 + 2]);
                z[n][q * 4 + 3] = fdot2(ep, w4.w, z[n][q * 4 + 3]);
            }
        }
    }
    float lg[NE];
#pragma unroll
    for (int n = 0; n < NE; ++n) {
        float t = 0.f;
#pragma unroll
        for (int c = 0; c < CPL; ++c) {
            float a = z[n][c] > 0.f ? z[n][c] : 0.2f * z[n][c];
            t = fmaf(att_r[c], a, t);
        }
        lg[n] = group_reduce<G>(t);
    }
    float mn = m;
#pragma unroll
    for (int n = 0; n < NE; ++n) mn = fmaxf(mn, lg[n]);
    float sc = fexp2(m - mn);
    float p[NE], ps = 0.f;
#pragma unroll
    for (int n = 0; n < NE; ++n) { p[n] = fexp2(lg[n] - mn); ps += p[n]; }
    m = mn;
    l = fmaf(l, sc, ps);
#pragma unroll
    for (int c = 0; c < CPL; ++c) {
        float t = p[0] * xv[0][c];
#pragma unroll
        for (int n = 1; n < NE; ++n) t = fmaf(p[n], xv[n][c], t);
        acc[c] = fmaf(acc[c], sc, t);
    }
}

template <int D, int C, int CB, int WPN, bool RELU>
__global__ __launch_bounds__(256) void attn_hase(
    const unsigned short* __restrict__ xlr, const uint4* __restrict__ ead4,
    const float* __restrict__ We, const float* __restrict__ att,
    const int* __restrict__ srcs, const int* __restrict__ off,
    const float* __restrict__ bias, unsigned short* __restrict__ outp, int N) {
    constexpr int CPL = CB / 64;
    constexpr int HW = CB / C;
    constexpr int G = 64 / HW;
    constexpr int NPB = 4 / WPN;
    // LDS We as half2 per (k-pair, channel): 4*D uints = 16D bytes (16 KB @ D=1024)
    __shared__ unsigned wsh[4 * D];
    for (int idx = threadIdx.x; idx < D; idx += 256) {
        int kp = idx / (D / 4);
        int t = idx - kp * (D / 4);
        int pos = 4 * t;              // uint offset within kp-plane
        int b = pos / CB;             // role block
        int r = pos - b * CB;
        int q = r >> 8;               // 256-uint q-blocks
        int ln4 = r - (q << 8);
        int cc = b * CB + (ln4 >> 2) * CPL + q * 4;   // global channel of elem 0
        float4 w0 = *(const float4*)(We + (size_t)(2 * kp) * D + cc);
        float4 w1 = *(const float4*)(We + (size_t)(2 * kp + 1) * D + cc);
        uint4 o;
        o.x = packh2(w0.x, w1.x);
        o.y = packh2(w0.y, w1.y);
        o.z = packh2(w0.z, w1.z);
        o.w = packh2(w0.w, w1.w);
        ((uint4*)wsh)[idx] = o;
    }
    __syncthreads();

    const int wid = threadIdx.x >> 6, lane = threadIdx.x & 63;
    const int wv = wid % WPN, wn = wid / WPN;
    const int c0 = wv * CB + lane * CPL;
    const unsigned* wbu = wsh + wv * CB + lane * 4;

    const float L2E = 1.4426950408889634f;   // exp2-domain softmax
    float att_r[CPL];
#pragma unroll
    for (int c = 0; c < CPL; ++c) att_r[c] = att[c0 + c] * L2E;

    for (int node = blockIdx.x * NPB + wn; node < N; node += gridDim.x * NPB) {
        typename RawT<CPL>::T xrw =
            *(const typename RawT<CPL>::T*)(xlr + (size_t)node * (2 * D) + D + c0);
        float xr_r[CPL];
        unpackx<CPL>(xrw, xr_r);
        float m = -1e30f, l = 0.f, acc[CPL];
#pragma unroll
        for (int c = 0; c < CPL; ++c) acc[c] = 0.f;

        const int jb = __builtin_amdgcn_readfirstlane(off[node]);
        const int je = __builtin_amdgcn_readfirstlane(off[node + 1]);
        int j = jb;
        for (; j + 4 <= je; j += 4)
            hase_group<D, CPL, G, 4>(xlr, ead4 + j, srcs + j, wbu, att_r, xr_r, c0, m, l, acc);
        for (; j < je; ++j)
            hase_group<D, CPL, G, 1>(xlr, ead4 + j, srcs + j, wbu, att_r, xr_r, c0, m, l, acc);

        float inv = 1.f / (l + 1e-16f);
        float r[CPL];
#pragma unroll
        for (int c = 0; c < CPL; ++c) {
            r[c] = fmaf(acc[c], inv, bias[c0 + c]);
            if constexpr (RELU) r[c] = fmaxf(r[c], 0.f);
        }
        store_bf16v<CPL>(outp + (size_t)node * D + c0, r);
    }
}

// ---------- fused attention, no edge_attr (layer 3) ----------
template <int D, int CPL, int G, int NE>
static __device__ __forceinline__ void noe_group(
    const unsigned short* __restrict__ xlr, const int* __restrict__ sj,
    const float (&att_r)[CPL], const float (&xr_r)[CPL], int c0,
    float& m, float& l, float (&acc)[CPL]) {
    int src[NE];
#pragma unroll
    for (int n = 0; n < NE; ++n) src[n] = sj[n];
    float xv[NE][CPL], lg[NE];
#pragma unroll
    for (int n = 0; n < NE; ++n) {
        typename RawT<CPL>::T xw =
            *(const typename RawT<CPL>::T*)(xlr + (size_t)src[n] * (2 * D) + c0);
        unpackx<CPL>(xw, xv[n]);
    }
#pragma unroll
    for (int n = 0; n < NE; ++n) {
        float t = 0.f;
#pragma unroll
        for (int c = 0; c < CPL; ++c) {
            float z = xv[n][c] + xr_r[c];
            z = z > 0.f ? z : 0.2f * z;
            t = fmaf(att_r[c], z, t);
        }
        lg[n] = group_reduce<G>(t);
    }
    float mn = m;
#pragma unroll
    for (int n = 0; n < NE; ++n) mn = fmaxf(mn, lg[n]);
    float sc = fexp2(m - mn);
    float p[NE], ps = 0.f;
#pragma unroll
    for (int n = 0; n < NE; ++n) { p[n] = fexp2(lg[n] - mn); ps += p[n]; }
    m = mn;
    l = fmaf(l, sc, ps);
#pragma unroll
    for (int c = 0; c < CPL; ++c) {
        float t = p[0] * xv[0][c];
#pragma unroll
        for (int n = 1; n < NE; ++n) t = fmaf(p[n], xv[n][c], t);
        acc[c] = fmaf(acc[c], sc, t);
    }
}

template <int D, int C, int CB, bool RELU>
static __device__ __forceinline__ void attn_wave3(
    const unsigned short* __restrict__ xlr, const float* __restrict__ att,
    const int* __restrict__ srcs, int jb, int je,
    const float* __restrict__ bias, float* __restrict__ outp,
    int node, int cb, int lane) {
    constexpr int CPL = CB / 64;
    constexpr int HW = CB / C;
    constexpr int G = 64 / HW;
    const int c0 = cb + lane * CPL;
    const float L2E = 1.4426950408889634f;

    typename RawT<CPL>::T xrw =
        *(const typename RawT<CPL>::T*)(xlr + (size_t)node * (2 * D) + D + c0);
    float xr_r[CPL], att_r[CPL];
    unpackx<CPL>(xrw, xr_r);
#pragma unroll
    for (int c = 0; c < CPL; ++c) att_r[c] = att[c0 + c] * L2E;

    float m = -1e30f, l = 0.f, acc[CPL];
#pragma unroll
    for (int c = 0; c < CPL; ++c) acc[c] = 0.f;

    int j = jb;
    for (; j + 4 <= je; j += 4)
        noe_group<D, CPL, G, 4>(xlr, srcs + j, att_r, xr_r, c0, m, l, acc);
    for (; j < je; ++j)
        noe_group<D, CPL, G, 1>(xlr, srcs + j, att_r, xr_r, c0, m, l, acc);

    float inv = 1.f / (l + 1e-16f);
    float* out = outp + (size_t)node * D + c0;
    float tmp[CPL];
#pragma unroll
    for (int c = 0; c < CPL; ++c) {
        float r = fmaf(acc[c], inv, bias[c0 + c]);
        if constexpr (RELU) r = fmaxf(r, 0.f);
        tmp[c] = r;
    }
    if constexpr (CPL == 4) *(float4*)out = *(float4*)tmp;
    else if constexpr (CPL == 2) *(float2*)out = *(float2*)tmp;
    else out[0] = tmp[0];
}

template <int D, int C, int CB0, int CB1, bool RELU>
__global__ __launch_bounds__(256) void attn_noe(
    const unsigned short* __restrict__ xlr, const float* __restrict__ att,
    const int* __restrict__ srcs, const int* __restrict__ off,
    const float* __restrict__ bias, float* __restrict__ outp, int N) {
    const int wid = threadIdx.x >> 6, lane = threadIdx.x & 63;
    const int gw = blockIdx.x * 4 + wid;
    const int node = gw >> 1, wv = gw & 1;
    if (node >= N) return;
    const int jb = __builtin_amdgcn_readfirstlane(off[node]);
    const int je = __builtin_amdgcn_readfirstlane(off[node + 1]);
    if (wv == 0)
        attn_wave3<D, C, CB0, RELU>(xlr, att, srcs, jb, je, bias, outp, node, 0, lane);
    else
        attn_wave3<D, C, CB1, RELU>(xlr, att, srcs, jb, je, bias, outp, node, CB0, lane);
}

// ---------- head: 2-layer MLP on master (last) node of each graph ----------
__global__ void mlp_kernel(const float* __restrict__ h3, const int* __restrict__ nn,
                           const float* __restrict__ Wfc1, const float* __restrict__ bfc1,
                           const float* __restrict__ Wfc2, const float* __restrict__ bfc2,
                           float* __restrict__ out, int G) {
    int g = blockIdx.x, t = threadIdx.x;  // 64 threads
    int s = 0;
    for (int k = 0; k <= g; ++k) s += nn[k];
    const float* row = h3 + (size_t)(s - 1) * 384;
    float z = bfc1[t];
    for (int k = 0; k < 384; ++k) z = fmaf(row[k], Wfc1[k * 64 + t], z);
    z = fmaxf(z, 0.f);
    float v = z * Wfc2[t];
#pragma unroll
    for (int o = 32; o; o >>= 1) v += __shfl_xor(v, o, 64);
    if (t == 0) out[g] = v + bfc2[0];
}

extern "C" void kernel_launch(void* const* d_in, const int* in_sizes, int n_in,
                              void* d_out, int out_size, void* d_ws, size_t ws_size,
                              hipStream_t stream) {
    const float* x    = (const float*)d_in[0];
    const float* ea   = (const float*)d_in[1];
    const float* Wl1  = (const float*)d_in[2];
    const float* Wr1  = (const float*)d_in[3];
    const float* We1  = (const float*)d_in[4];
    const float* att1 = (const float*)d_in[5];
    const float* b1   = (const float*)d_in[6];
    const float* Wl2  = (const float*)d_in[7];
    const float* Wr2  = (const float*)d_in[8];
    const float* We2  = (const float*)d_in[9];
    const float* att2 = (const float*)d_in[10];
    const float* b2   = (const float*)d_in[11];
    const float* Wlp  = (const float*)d_in[12];
    const float* Wrp  = (const float*)d_in[13];
    const float* attp = (const float*)d_in[14];
    const float* bp   = (const float*)d_in[15];
    const float* Wfc1 = (const float*)d_in[16];
    const float* bfc1 = (const float*)d_in[17];
    const float* Wfc2 = (const float*)d_in[18];
    const float* bfc2 = (const float*)d_in[19];
    const int* ei     = (const int*)d_in[20];
    const int* eim    = (const int*)d_in[21];
    const int* nn     = (const int*)d_in[22];

    const int N = in_sizes[0] / 64;   // 20000
    const int E = in_sizes[20] / 2;   // 160000
    const int G = in_sizes[22];       // 100
    const int* src1 = ei,  *dst1 = ei + E;
    const int* srcm = eim, *dstm = eim + E;

    // ---- workspace layout (unchanged footprint) ----
    char* w = (char*)d_ws;
    size_t o = 0;
    auto alloc = [&](size_t b) { size_t r = o; o += (b + 255) & ~(size_t)255; return r; };
    char* R1 = w + alloc((size_t)N * 2048 * 2);
    unsigned short* xlr1 = (unsigned short*)R1;
    unsigned short* xlr3 = (unsigned short*)R1;
    float* h3 = (float*)(R1 + (size_t)N * 768 * 2 + 256);
    unsigned short* h1   = (unsigned short*)(w + alloc((size_t)N * 1024 * 2));
    unsigned short* xlr2 = (unsigned short*)(w + alloc((size_t)N * 512 * 2));
    unsigned short* h2   = (unsigned short*)(w + alloc((size_t)N * 256 * 2));
    unsigned short* xbf  = (unsigned short*)(w + alloc((size_t)N * 64 * 2));
    unsigned short* wt1  = (unsigned short*)(w + alloc((size_t)2048 * 64 * 2));
    unsigned short* wt2  = (unsigned short*)(w + alloc((size_t)512 * 1024 * 2));
    unsigned short* wt3  = (unsigned short*)(w + alloc((size_t)768 * 256 * 2));
    int*  cnt   = (int*)(w + alloc((size_t)2 * N * 4));
    int*  off   = (int*)(w + alloc((size_t)2 * (N + 1) * 4));
    int*  cur   = (int*)(w + alloc((size_t)2 * N * 4));
    char* eReg  = w + alloc((size_t)2 * E * 8 + 4096);
    int2* edges = (int2*)eReg;
    int*  srcs  = (int*)(eReg + (size_t)E * 8);
    (void)ws_size; (void)n_in; (void)out_size;

    // dead-region reuse (zero extra footprint):
    uint4* ead1 = (uint4*)xlr2;   // E*16 B = 2.56 MB <= 20.48 MB, dead until gemm2
    uint4* ead2 = (uint4*)h1;     // dead after gemm2 consumed h1

    dim3 blk(256);

    // ---- weight prep (single merged launch) ----
    {
        int tot = 2 * 64 * 1024 + 2 * 1024 * 256 + 2 * 256 * 384 + N * 64;
        prep_all<<<DIV_UP(tot, 256), blk, 0, stream>>>(x, Wl1, Wr1, Wl2, Wr2, Wlp, Wrp,
                                                       xbf, wt1, wt2, wt3, N);
    }

    // ---- CSR for both graphs ----
    hipMemsetAsync(cnt, 0, (size_t)2 * N * 4, stream);
    count2_kernel<<<DIV_UP(2 * E, 256), blk, 0, stream>>>(dst1, dstm, E, N, cnt);
    scan_kernel<<<2, 1024, 0, stream>>>(cnt, N, off, cur);
    fill2_kernel<<<DIV_UP(2 * E, 256), blk, 0, stream>>>(src1, dst1, srcm, dstm, E, N, cur,
                                                         edges, srcs);
    ea_gather_kernel<<<DIV_UP(E, 256), blk, 0, stream>>>(ea, edges, ead1, E);
    const int* off3 = off + (N + 1);
    const int* srcs3 = srcs + E;

    // ---- Layer 1: H=4, C=256, D=1024 — 2 waves/node, CPL=8, G=32 ----
    gemm_mfma<<<dim3(2048 / 128, DIV_UP(N, 128)), blk, 0, stream>>>(xbf, wt1, xlr1, N, 2048, 64);
    attn_hase<1024, 256, 512, 2, true><<<2560, blk, 0, stream>>>(
        xlr1, ead1, We1, att1, srcs, off, b1, h1, N);

    // ---- Layer 2: H=4, C=64, D=256 — 1 wave/node, CPL=4, G=16 ----
    gemm_mfma<<<dim3(512 / 128, DIV_UP(N, 128)), blk, 0, stream>>>(h1, wt2, xlr2, N, 512, 1024);
    ea_gather_kernel<<<DIV_UP(E, 256), blk, 0, stream>>>(ea, edges, ead2, E);
    attn_hase<256, 64, 256, 1, true><<<1280, blk, 0, stream>>>(
        xlr2, ead2, We2, att2, srcs, off, b2, h2, N);

    // ---- Layer 3: H=6, C=64, D=384 — 2 waves/node (roles 256/128), fp32 out ----
    gemm_mfma<<<dim3(768 / 128, DIV_UP(N, 128)), blk, 0, stream>>>(h2, wt3, xlr3, N, 768, 256);
    attn_noe<384, 64, 256, 128, false><<<DIV_UP(N, 2), blk, 0, stream>>>(
        xlr3, attp, srcs3, off3, bp, h3, N);

    // ---- head ----
    mlp_kernel<<<G, 64, 0, stream>>>(h3, nn, Wfc1, bfc1, Wfc2, bfc2, (float*)d_out, G);
}